// Round 3
// baseline (515.493 us; speedup 1.0000x reference)
//
#include <hip/hip_runtime.h>
#include <hip/hip_bf16.h>

#define RMAX 40
#define HH   512
#define WW   512
#define CC   3
#define BB   64
#define HT   16    // h-rows per passB block
#define LROW 640   // LDS row length in shorts (1280 B, multiple of 64 shorts for XOR swizzle)

typedef unsigned short u16;
typedef _Float16 half8 __attribute__((ext_vector_type(8)));   // 8 f16 = 4 VGPR MFMA A/B frag
typedef __attribute__((ext_vector_type(8))) short short8;
typedef __attribute__((ext_vector_type(4))) float f32x4;      // MFMA C/D frag

__device__ __forceinline__ u16 h2u(_Float16 h) { return __builtin_bit_cast(u16, h); }

// ---------------------------------------------------------------------------
// prep: per-sample radius, 3x3 channel-mix matrix, and the f16 hi/lo Toeplitz
// A-fragment table shared by BOTH conv passes (the 1-D Gaussian is the same
// matrix along w and h). Chunk bases are aligned down by delta=(-r)&7 so that
// all B-fragment vector loads are 16B-aligned; delta is folded into the
// weight index here (block-independent because all tiles are 32-aligned).
// atab[b][16 slots][64 lanes][8]: slot s = ch*4 + half*2 + prec;
//   A[i][kk] = kz[32*ch + kk - i - 16*half - delta], i = lane&15,
//   kk = 8*(lane>>4)+j; prec0 = f16(w) "hi", prec1 = f16(w - hi) "lo".
// ---------------------------------------------------------------------------
__global__ __launch_bounds__(256) void prep_kernel(
    const float* __restrict__ sigmas10,
    const int*   __restrict__ steps,
    int*   __restrict__ rbuf,
    float* __restrict__ mbuf,
    u16*   __restrict__ atab)
{
    const int b   = blockIdx.x;
    const int tid = threadIdx.x;
    const float sigma = sigmas10[steps[b]];
    int r = (int)floorf(4.0f * sigma + 0.5f);
    if (r > RMAX) r = RMAX;
    const float s2 = sigma * sigma;

    float sum = 0.0f;
    for (int p = -r; p <= r; ++p)
        sum += expf(-0.5f * (float)(p * p) / s2);
    const float inv = 1.0f / sum;

    if (tid == 0) {
        rbuf[b] = r;
        float Mm[9];
        for (int i = 0; i < 9; ++i) Mm[i] = 0.0f;
        for (int p = -r; p <= r; ++p) {
            float wv = expf(-0.5f * (float)(p * p) / s2) * inv;
            for (int c = 0; c < CC; ++c) {
                int i = c + p;
                int j = ((i % 6) + 6) % 6;     // reflect for n=3 -> period 6
                int cc = (j < 3) ? j : 5 - j;
                Mm[c * 3 + cc] += wv;
            }
        }
        for (int c = 0; c < 3; ++c)
            for (int cc = 0; cc < 3; ++cc)
                mbuf[b * 12 + c * 4 + cc] = Mm[c * 3 + cc];
    }

    const int dlt = (-r) & 7;
    u16* ab = atab + (size_t)b * 8192;
    int e = tid * 32;
    for (int ee = 0; ee < 32; ++ee, ++e) {
        int j    = e & 7;
        int lane = (e >> 3) & 63;
        int s    = e >> 9;          // 0..15
        int ch   = s >> 2;          // K-chunk of 32
        int half = (s >> 1) & 1;    // output half (i or i+16)
        int prec = s & 1;           // 0=hi, 1=lo
        int m = 32 * ch + ((lane >> 4) << 3) + j - (lane & 15) - 16 * half - dlt;
        float wfull = 0.0f;
        if (m >= 0 && m <= 2 * r) {
            int p = m - r;
            wfull = expf(-0.5f * (float)(p * p) / s2) * inv;
        }
        _Float16 hi = (_Float16)wfull;
        _Float16 val = prec ? (_Float16)(wfull - (float)hi) : hi;
        ab[e] = h2u(val);
    }
}

// ---------------------------------------------------------------------------
// passB: channel mix + W-axis conv via MFMA, writing inter TRANSPOSED [w][h]
// in f16. Block = (b, 16 h-rows), 512 threads, LDS 60 KiB -> 2 blocks/CU.
// Staging: reflect-extended mixed rows as f16 into LDS, XOR-swizzled
// (byte ^= (h&7)<<4) so the 16-rows-same-cols B-read is conflict-free (T2).
// Compute: 48 wave-tasks (3 c x 16 w-tiles of 32); per task D[i=w][col=h],
// per chunk 1 ds_read_b128 + 4 A dwordx4 (L2-hot) + 4 f16 MFMAs (hi/lo x 2
// halves). Stores: 2B scalars, 16 lanes contiguous = 32B segments.
// ---------------------------------------------------------------------------
__global__ __launch_bounds__(512) void passB_kernel(
    const float* __restrict__ x,
    const u16*   __restrict__ atab,
    const float* __restrict__ mbuf,
    const int*   __restrict__ rbuf,
    u16* __restrict__ interT)
{
    __shared__ __align__(16) u16 mixs[CC][HT][LROW];   // f16 bits, swizzled

    const int b   = blockIdx.y;
    const int h0  = blockIdx.x * HT;
    const int tid = threadIdx.x;
    const int r   = __builtin_amdgcn_readfirstlane(rbuf[b]);

    const float M00 = mbuf[b * 12 + 0], M01 = mbuf[b * 12 + 1], M02 = mbuf[b * 12 + 2];
    const float M10 = mbuf[b * 12 + 4], M11 = mbuf[b * 12 + 5], M12 = mbuf[b * 12 + 6];
    const float M20 = mbuf[b * 12 + 8], M21 = mbuf[b * 12 + 9], M22 = mbuf[b * 12 + 10];

    const float* xb = x + (size_t)b * CC * HH * WW + (size_t)h0 * WW;

    // stage 16 h x 640 w positions (logical w -40..599, reflected), 20 iters
    for (int idx = tid; idx < HT * LROW; idx += 512) {
        int h  = idx / LROW;
        int wi = idx - h * LROW;
        int lw = wi - RMAX;                  // logical w
        int jm = lw & (2 * WW - 1);
        int src = (jm < WW) ? jm : (2 * WW - 1 - jm);
        const float* px = xb + (size_t)h * WW + src;
        float a0 = __builtin_nontemporal_load(px);
        float a1 = __builtin_nontemporal_load(px + HH * WW);
        float a2 = __builtin_nontemporal_load(px + 2 * HH * WW);
        int sw = wi ^ ((h & 7) << 3);        // 16B-granule XOR swizzle
        mixs[0][h][sw] = h2u((_Float16)(M00 * a0 + M01 * a1 + M02 * a2));
        mixs[1][h][sw] = h2u((_Float16)(M10 * a0 + M11 * a1 + M12 * a2));
        mixs[2][h][sw] = h2u((_Float16)(M20 * a0 + M21 * a1 + M22 * a2));
    }
    __syncthreads();

    const int dlt  = (-r) & 7;
    const int nch  = (2 * r + dlt + 63) >> 5;    // <= 4
    const int lane = tid & 63;
    const int wv   = tid >> 6;
    const int col  = lane & 15;                  // h-col of D
    const int g    = lane >> 4;
    const half8* at = (const half8*)(atab + (size_t)b * 8192);

    for (int task = wv; task < 48; task += 8) {
        const int c  = task >> 4;
        const int w0 = (task & 15) << 5;
        const int s0w = (w0 + RMAX - r) & ~7;    // aligned LDS window start
        const u16* lrow = &mixs[c][col][0];

        f32x4 acc0 = {0.f, 0.f, 0.f, 0.f};
        f32x4 acc1 = {0.f, 0.f, 0.f, 0.f};
        for (int ch = 0; ch < nch; ++ch) {
            int wi = (s0w + 32 * ch + 8 * g) ^ ((col & 7) << 3);
            half8 bv  = *(const half8*)(lrow + wi);          // ds_read_b128
            half8 ah0 = at[(ch * 4 + 0) * 64 + lane];
            half8 al0 = at[(ch * 4 + 1) * 64 + lane];
            half8 ah1 = at[(ch * 4 + 2) * 64 + lane];
            half8 al1 = at[(ch * 4 + 3) * 64 + lane];
            acc0 = __builtin_amdgcn_mfma_f32_16x16x32_f16(ah0, bv, acc0, 0, 0, 0);
            acc0 = __builtin_amdgcn_mfma_f32_16x16x32_f16(al0, bv, acc0, 0, 0, 0);
            acc1 = __builtin_amdgcn_mfma_f32_16x16x32_f16(ah1, bv, acc1, 0, 0, 0);
            acc1 = __builtin_amdgcn_mfma_f32_16x16x32_f16(al1, bv, acc1, 0, 0, 0);
        }
        // D rows i = 4g+q (acc0) / 16+4g+q (acc1), col = h0+col; inter[w][h]
        u16* orow = interT + (((size_t)b * CC + c) * WW + (w0 + 4 * g)) * HH
                  + h0 + col;
#pragma unroll
        for (int q = 0; q < 4; ++q) {
            orow[(size_t)q * HH]        = h2u((_Float16)acc0[q]);
            orow[(size_t)(q + 16) * HH] = h2u((_Float16)acc1[q]);
        }
    }
}

// ---------------------------------------------------------------------------
// passC: H-axis conv via MFMA from transposed f16 inter. B-fragment is now a
// single 16B dwordx4 per lane per chunk (interior fast path; reflect gather
// only for boundary h-tiles). Same atab. Stores 64B-coalesced fp32.
// ---------------------------------------------------------------------------
__device__ __forceinline__ int refl512(int i) {
    int jm = i & (2 * HH - 1);
    return (jm < HH) ? jm : (2 * HH - 1 - jm);
}

__global__ __launch_bounds__(256) void passC_kernel(
    const u16* __restrict__ interT,
    const u16* __restrict__ atab,
    const int* __restrict__ rbuf,
    float* __restrict__ out)
{
    const int tid  = threadIdx.x;
    const int lane = tid & 63;
    const int bc   = blockIdx.z;
    const int b    = bc / 3;
    const int r    = __builtin_amdgcn_readfirstlane(rbuf[b]);
    const int dlt  = (-r) & 7;
    const int nch  = (2 * r + dlt + 63) >> 5;
    const int h0   = blockIdx.y * 32;
    const int w    = blockIdx.x * 64 + (tid >> 6) * 16 + (lane & 15);
    const int s0   = (h0 - r) & ~7;          // aligned window start (can be <0)
    const int g    = lane >> 4;

    const u16* wrow = interT + ((size_t)bc * WW + w) * HH;
    const half8* at = (const half8*)(atab + (size_t)b * 8192);
    const bool fast = (s0 >= 0) && (s0 + 32 * nch <= HH);   // block-uniform

    f32x4 acc0 = {0.f, 0.f, 0.f, 0.f};
    f32x4 acc1 = {0.f, 0.f, 0.f, 0.f};

    for (int ch = 0; ch < nch; ++ch) {
        short8 braw;
        if (fast) {
            braw = *(const short8*)(wrow + s0 + 32 * ch + 8 * g);
        } else {
#pragma unroll
            for (int j = 0; j < 8; ++j)
                braw[j] = (short)wrow[refl512(s0 + 32 * ch + 8 * g + j)];
        }
        half8 bv  = __builtin_bit_cast(half8, braw);
        half8 ah0 = at[(ch * 4 + 0) * 64 + lane];
        half8 al0 = at[(ch * 4 + 1) * 64 + lane];
        half8 ah1 = at[(ch * 4 + 2) * 64 + lane];
        half8 al1 = at[(ch * 4 + 3) * 64 + lane];
        acc0 = __builtin_amdgcn_mfma_f32_16x16x32_f16(ah0, bv, acc0, 0, 0, 0);
        acc0 = __builtin_amdgcn_mfma_f32_16x16x32_f16(al0, bv, acc0, 0, 0, 0);
        acc1 = __builtin_amdgcn_mfma_f32_16x16x32_f16(ah1, bv, acc1, 0, 0, 0);
        acc1 = __builtin_amdgcn_mfma_f32_16x16x32_f16(al1, bv, acc1, 0, 0, 0);
    }

    const int orow = h0 + 4 * g;
    float* dst = out + (size_t)bc * HH * WW + (size_t)orow * WW + w;
#pragma unroll
    for (int q = 0; q < 4; ++q) {
        __builtin_nontemporal_store(acc0[q], dst + (size_t)q * WW);
        __builtin_nontemporal_store(acc1[q], dst + (size_t)(q + 16) * WW);
    }
}

// ---------------------------------------------------------------------------
extern "C" void kernel_launch(void* const* d_in, const int* in_sizes, int n_in,
                              void* d_out, int out_size, void* d_ws, size_t ws_size,
                              hipStream_t stream)
{
    const float* x      = (const float*)d_in[0];
    const float* sigmas = (const float*)d_in[1];
    const int*   steps  = (const int*)d_in[2];
    float*       out    = (float*)d_out;

    int*   rbuf   = (int*)d_ws;                               // 256 B
    float* mbuf   = (float*)((char*)d_ws + 256);              // 3 KB
    u16*   atab   = (u16*)((char*)d_ws + 4096);               // 1 MiB
    u16*   interT = (u16*)((char*)d_ws + 4096 + (1 << 20));   // 96 MiB f16 [w][h]

    prep_kernel<<<64, 256, 0, stream>>>(sigmas, steps, rbuf, mbuf, atab);

    passB_kernel<<<dim3(HH / HT, BB), 512, 0, stream>>>(x, atab, mbuf, rbuf, interT);

    passC_kernel<<<dim3(WW / 64, HH / 32, BB * CC), 256, 0, stream>>>(interT, atab, rbuf, out);
}

// Round 5
// 409.313 us; speedup vs baseline: 1.2594x; 1.2594x over previous
//
#include <hip/hip_runtime.h>
#include <hip/hip_bf16.h>

#define RMAX 40
#define LK   81
#define HH   512
#define WW   512
#define CC   3
#define BB   64
#define ROWS 2    // h-rows per passB block

typedef unsigned short u16;
typedef __attribute__((ext_vector_type(8))) short short8;   // 8 bf16 (4 VGPR) MFMA A/B frag
typedef __attribute__((ext_vector_type(4))) float f32x4;    // MFMA C/D frag + 16B vec loads

// bf16 round-to-nearest-even pack/unpack (values here are finite, no NaN)
__device__ __forceinline__ u16 f2bf(float f) {
    unsigned u = __float_as_uint(f);
    u += 0x7FFFu + ((u >> 16) & 1u);
    return (u16)(u >> 16);
}
__device__ __forceinline__ float bf2f(u16 s) {
    return __uint_as_float(((unsigned)s) << 16);
}

// ---------------------------------------------------------------------------
// Kernel A (prep), 64 blocks x 256 threads (one block per sample b):
//  - wbuf  [64][128]: zero-padded fp32 taps for passB (tap p at index 56+p)
//  - mbuf  [64][12]:  3x3 channel-mix matrix (C-axis conv through reflect-3)
//  - rbuf  [64]:      per-sample radius
//  - atab  [64][16 slots][64 lanes][8]: bf16 Toeplitz A-fragments for passC's
//    MFMA H-conv. slot s = ch*4 + half*2 + prec; A[i][kk] = kz[32*ch + kk - i
//    - 16*half], lane i = lane&15, kk = 8*(lane>>4)+j. prec0 = bf16(w) ("hi"),
//    prec1 = bf16(w - hi) ("lo") so hi+lo carries fp32-grade weights.
// ---------------------------------------------------------------------------
__global__ __launch_bounds__(256) void prep_kernel(
    const float* __restrict__ sigmas10,
    const int*   __restrict__ steps,
    int*   __restrict__ rbuf,
    float* __restrict__ mbuf,
    float* __restrict__ wbuf,
    u16*   __restrict__ atab)
{
    const int b   = blockIdx.x;
    const int tid = threadIdx.x;
    const float sigma = sigmas10[steps[b]];
    int r = (int)floorf(4.0f * sigma + 0.5f);
    if (r > RMAX) r = RMAX;
    const float s2 = sigma * sigma;

    float sum = 0.0f;
    for (int p = -r; p <= r; ++p)
        sum += expf(-0.5f * (float)(p * p) / s2);
    const float inv = 1.0f / sum;

    // fp32 taps for passB
    if (tid < 128) {
        int p = tid - 56;                      // index 16 + (p + RMAX)
        float v = 0.0f;
        if (p >= -r && p <= r)
            v = expf(-0.5f * (float)(p * p) / s2) * inv;
        wbuf[b * 128 + tid] = v;
    }

    if (tid == 0) {
        rbuf[b] = r;
        float Mm[9];
        for (int i = 0; i < 9; ++i) Mm[i] = 0.0f;
        for (int p = -r; p <= r; ++p) {
            float wv = expf(-0.5f * (float)(p * p) / s2) * inv;
            for (int c = 0; c < CC; ++c) {
                int i = c + p;
                int j = ((i % 6) + 6) % 6;     // reflect for n=3 -> period 6
                int cc = (j < 3) ? j : 5 - j;
                Mm[c * 3 + cc] += wv;
            }
        }
        for (int c = 0; c < 3; ++c)
            for (int cc = 0; cc < 3; ++cc)
                mbuf[b * 12 + c * 4 + cc] = Mm[c * 3 + cc];
    }

    // A-fragment table: 16 slots x 64 lanes x 8 = 8192 bf16 per sample
    u16* ab = atab + (size_t)b * 8192;
    int e = tid * 32;
    for (int ee = 0; ee < 32; ++ee, ++e) {
        int j    = e & 7;
        int lane = (e >> 3) & 63;
        int s    = e >> 9;          // 0..15
        int ch   = s >> 2;          // K-chunk of 32
        int half = (s >> 1) & 1;    // output half (i or i+16)
        int prec = s & 1;           // 0=hi, 1=lo
        int m = 32 * ch + ((lane >> 4) << 3) + j - (lane & 15) - 16 * half;
        float wfull = 0.0f;
        if (m >= 0 && m <= 2 * r) {
            int p = m - r;
            wfull = expf(-0.5f * (float)(p * p) / s2) * inv;
        }
        u16 hi = f2bf(wfull);
        u16 val = hi;
        if (prec) val = f2bf(wfull - bf2f(hi));
        ab[e] = val;
    }
}

// ---------------------------------------------------------------------------
// Kernel B: fused channel mix + W-axis conv, bf16 output (R2 structure).
// One block per (b, 2 h-rows), 256 threads, LDS 14.2 KB -> 8 blocks/CU.
// R4 staging: interior = 1 float4 task/thread (3 coalesced 16B loads -> 12
// FMAs -> 3 ds_write_b128), halo = 160 threads x 3 scalar loads. Vector
// loads use ext_vector f32x4 (nontemporal builtin rejects HIP float4).
// ---------------------------------------------------------------------------
__global__ __launch_bounds__(256) void passB_kernel(
    const float* __restrict__ x,
    const float* __restrict__ wbuf,
    const float* __restrict__ mbuf,
    const int*   __restrict__ rbuf,
    u16* __restrict__ out1)
{
    __shared__ __align__(16) float mixed[CC * ROWS][WW + 2 * RMAX]; // [6][592]

    const int b   = blockIdx.y;
    const int h0  = blockIdx.x * ROWS;
    const int tid = threadIdx.x;
    const int r   = __builtin_amdgcn_readfirstlane(rbuf[b]);

    const float M00 = mbuf[b * 12 + 0], M01 = mbuf[b * 12 + 1], M02 = mbuf[b * 12 + 2];
    const float M10 = mbuf[b * 12 + 4], M11 = mbuf[b * 12 + 5], M12 = mbuf[b * 12 + 6];
    const float M20 = mbuf[b * 12 + 8], M21 = mbuf[b * 12 + 9], M22 = mbuf[b * 12 + 10];

    const float* xb = x + (size_t)b * CC * HH * WW + (size_t)h0 * WW;

    // ---- interior staging: one 4-wide task per thread (row = tid>>7) ------
    {
        const int row   = tid >> 7;          // 0..1
        const int wbase = (tid & 127) << 2;  // 0,4,..,508
        const float* px = xb + (size_t)row * WW + wbase;
        f32x4 c0 = __builtin_nontemporal_load((const f32x4*)px);
        f32x4 c1 = __builtin_nontemporal_load((const f32x4*)(px + HH * WW));
        f32x4 c2 = __builtin_nontemporal_load((const f32x4*)(px + 2 * HH * WW));
        f32x4 m0 = M00 * c0 + M01 * c1 + M02 * c2;
        f32x4 m1 = M10 * c0 + M11 * c1 + M12 * c2;
        f32x4 m2 = M20 * c0 + M21 * c1 + M22 * c2;
        *(f32x4*)&mixed[0 * ROWS + row][RMAX + wbase] = m0;   // rc = c*2+row
        *(f32x4*)&mixed[1 * ROWS + row][RMAX + wbase] = m1;
        *(f32x4*)&mixed[2 * ROWS + row][RMAX + wbase] = m2;
    }
    // ---- halo staging: 160 threads, one reflected position each -----------
    if (tid < 2 * 2 * RMAX) {
        const int row = tid & 1;
        const int k   = tid >> 1;                      // 0..79
        const int wi  = (k < RMAX) ? k : (WW + k);     // [0,40) U [552,592)
        const int lw  = wi - RMAX;
        const int jm  = lw & (2 * WW - 1);
        const int src = (jm < WW) ? jm : (2 * WW - 1 - jm);
        const float* px = xb + (size_t)row * WW + src;
        float a0 = __builtin_nontemporal_load(px);
        float a1 = __builtin_nontemporal_load(px + HH * WW);
        float a2 = __builtin_nontemporal_load(px + 2 * HH * WW);
        mixed[0 * ROWS + row][wi] = M00 * a0 + M01 * a1 + M02 * a2;
        mixed[1 * ROWS + row][wi] = M10 * a0 + M11 * a1 + M12 * a2;
        mixed[2 * ROWS + row][wi] = M20 * a0 + M21 * a1 + M22 * a2;
    }
    __syncthreads();

    const int t0    = (RMAX - r) & ~3;                  // aligned first tap
    const int n4    = ((r + RMAX + 3 - t0) >> 2) + 1;   // float4 iterations
    const int kbase = (16 + t0) >> 2;
    const f32x4* K4 = (const f32x4*)(wbuf + b * 128);

#pragma unroll
    for (int k = 0; k < 3; ++k) {
        const int task = tid + 256 * k;     // 0..767
        const int g    = task & 127;
        const int rc   = task >> 7;         // 0..5  (c = rc>>1, row = rc&1)
        const int w0   = g << 2;

        const int dbase = (w0 + t0) >> 2;
        const f32x4* D4 = (const f32x4*)(&mixed[rc][0]);

        f32x4 Wlo = K4[kbase - 1];
        float acc0 = 0.f, acc1 = 0.f, acc2 = 0.f, acc3 = 0.f;

        for (int s = 0; s < n4; ++s) {
            f32x4 Whi = K4[kbase + s];      // uniform -> scalar load
            f32x4 D   = D4[dbase + s];      // ds_read_b128, conflict-free
            acc0 += Whi.x * D.x; acc1 += Wlo.w * D.x; acc2 += Wlo.z * D.x; acc3 += Wlo.y * D.x;
            acc0 += Whi.y * D.y; acc1 += Whi.x * D.y; acc2 += Wlo.w * D.y; acc3 += Wlo.z * D.y;
            acc0 += Whi.z * D.z; acc1 += Whi.y * D.z; acc2 += Whi.x * D.z; acc3 += Wlo.w * D.z;
            acc0 += Whi.w * D.w; acc1 += Whi.z * D.w; acc2 += Whi.y * D.w; acc3 += Whi.x * D.w;
            Wlo = Whi;
        }

        ushort4 o;
        o.x = f2bf(acc0); o.y = f2bf(acc1); o.z = f2bf(acc2); o.w = f2bf(acc3);
        const int c = rc >> 1, row = rc & 1;
        u16* dst = out1 + ((size_t)b * CC + c) * HH * WW
                 + (size_t)(h0 + row) * WW + w0;
        *(ushort4*)dst = o;                  // 8B aligned (w0 % 4 == 0)
    }
}

// ---------------------------------------------------------------------------
// Kernel C: H-axis conv as MFMA (R2 version, unchanged). D = A*B with A the
// precomputed hi/lo bf16 Toeplitz, B = inter rows (bf16, row-major).
// ---------------------------------------------------------------------------
__device__ __forceinline__ int refl512(int i) {
    int jm = i & (2 * HH - 1);              // mod 1024, ok for i >= -1024
    return (jm < HH) ? jm : (2 * HH - 1 - jm);
}

__global__ __launch_bounds__(256) void passC_kernel(
    const u16* __restrict__ in1,
    const u16* __restrict__ atab,
    const int* __restrict__ rbuf,
    float* __restrict__ out)
{
    const int tid  = threadIdx.x;
    const int lane = tid & 63;
    const int bc   = blockIdx.z;            // b*3 + c
    const int b    = bc / 3;
    const int r    = __builtin_amdgcn_readfirstlane(rbuf[b]);
    const int h0   = blockIdx.y * 32;
    const int w    = blockIdx.x * 64 + (tid >> 6) * 16 + (lane & 15);
    const int nch  = (2 * r + 63) >> 5;     // ceil((2r+32)/32), 2..4
    const int rowbase = h0 - r + ((lane >> 4) << 3);

    const u16* src = in1 + (size_t)bc * HH * WW + w;
    const short8* at = (const short8*)(atab + (size_t)b * 8192);

    f32x4 acc0 = {0.f, 0.f, 0.f, 0.f};
    f32x4 acc1 = {0.f, 0.f, 0.f, 0.f};

    for (int ch = 0; ch < nch; ++ch) {
        short8 bv;
#pragma unroll
        for (int j = 0; j < 8; ++j) {
            int row = refl512(rowbase + 32 * ch + j);
            bv[j] = (short)src[(size_t)row * WW];
        }
        short8 ah0 = at[(ch * 4 + 0) * 64 + lane];
        short8 al0 = at[(ch * 4 + 1) * 64 + lane];
        short8 ah1 = at[(ch * 4 + 2) * 64 + lane];
        short8 al1 = at[(ch * 4 + 3) * 64 + lane];

        acc0 = __builtin_amdgcn_mfma_f32_16x16x32_bf16(ah0, bv, acc0, 0, 0, 0);
        acc0 = __builtin_amdgcn_mfma_f32_16x16x32_bf16(al0, bv, acc0, 0, 0, 0);
        acc1 = __builtin_amdgcn_mfma_f32_16x16x32_bf16(ah1, bv, acc1, 0, 0, 0);
        acc1 = __builtin_amdgcn_mfma_f32_16x16x32_bf16(al1, bv, acc1, 0, 0, 0);
    }

    // C/D layout: col = lane&15 (== our w), row = 4*(lane>>4) + reg
    const int orow = h0 + ((lane >> 4) << 2);
    float* dst = out + (size_t)bc * HH * WW + (size_t)orow * WW + w;
#pragma unroll
    for (int q = 0; q < 4; ++q) {
        __builtin_nontemporal_store(acc0[q], dst + (size_t)q * WW);
        __builtin_nontemporal_store(acc1[q], dst + (size_t)(q + 16) * WW);
    }
}

// ---------------------------------------------------------------------------
extern "C" void kernel_launch(void* const* d_in, const int* in_sizes, int n_in,
                              void* d_out, int out_size, void* d_ws, size_t ws_size,
                              hipStream_t stream)
{
    const float* x      = (const float*)d_in[0];
    const float* sigmas = (const float*)d_in[1];
    const int*   steps  = (const int*)d_in[2];
    float*       out    = (float*)d_out;

    int*   rbuf  = (int*)d_ws;                              // 256 B
    float* mbuf  = (float*)((char*)d_ws + 256);             // 3 KB
    float* wbuf  = (float*)((char*)d_ws + 4096);            // 32 KB
    u16*   atab  = (u16*)((char*)d_ws + 65536);             // 1 MiB A-frag table
    u16*   inter = (u16*)((char*)d_ws + 65536 + (1 << 20)); // 96 MiB bf16

    prep_kernel<<<64, 256, 0, stream>>>(sigmas, steps, rbuf, mbuf, wbuf, atab);

    dim3 gB(HH / ROWS, BB);
    passB_kernel<<<gB, 256, 0, stream>>>(x, wbuf, mbuf, rbuf, inter);

    dim3 gC(WW / 64, HH / 32, BB * CC);
    passC_kernel<<<gC, 256, 0, stream>>>(inter, atab, rbuf, out);
}